// Round 2
// baseline (6039.999 us; speedup 1.0000x reference)
//
#include <hip/hip_runtime.h>

typedef unsigned short u16;
typedef __bf16 bf16x8 __attribute__((ext_vector_type(8)));
typedef float f32x4 __attribute__((ext_vector_type(4)));
typedef unsigned short u16x8 __attribute__((ext_vector_type(8)));

#define BB 1024
#define SS 256
#define DD 300
#define HH 150
#define GG 600
#define KSTR 320        // padded K stride for xe / h1
#define GSTR 608        // gates stride (600 rounded to 8)
#define WK 160          // padded Whh K stride

static __device__ __forceinline__ float bf2f(u16 u){
  unsigned v = ((unsigned)u) << 16;
  return __builtin_bit_cast(float, v);
}
static __device__ __forceinline__ u16 f2bf(float f){
  unsigned u = __builtin_bit_cast(unsigned, f);
  u = u + 0x7FFFu + ((u >> 16) & 1u);
  return (u16)(u >> 16);
}
static __device__ __forceinline__ float fsig(float x){
  return 1.0f / (1.0f + __expf(-x));
}
static __device__ __forceinline__ float ftanh_(float x){
  return 2.0f / (1.0f + __expf(-2.0f*x)) - 1.0f;
}

// ---------------- lengths from mask ----------------
__global__ void k_len(const int* __restrict__ mask, int* __restrict__ len){
  __shared__ int red[256];
  int b = blockIdx.x, t = threadIdx.x;
  red[t] = (mask[b*SS + t] != 0) ? 1 : 0;
  __syncthreads();
  for (int o = 128; o > 0; o >>= 1){
    if (t < o) red[t] += red[t+o];
    __syncthreads();
  }
  if (t == 0) len[b] = red[0];
}

// ---------------- deterministic rank sort by length (ascending) ----------------
__global__ void k_sort(const int* __restrict__ len, int* __restrict__ perm){
  __shared__ int L[1024];
  int b = threadIdx.x;
  int l = len[b];
  L[b] = l;
  __syncthreads();
  int r = 0;
  for (int j = 0; j < 1024; ++j){
    int lj = L[j];
    r += (lj < l) || (lj == l && j < b);
  }
  perm[r] = b;
}

// ---------------- weight pad/convert f32 -> bf16 ----------------
struct PrepW {
  const float* src[8];
  u16* dst[8];
  int R[8], C[8], DR[8], DC[8];
};
__global__ void k_prepw(PrepW p){
  int z = blockIdx.y;
  int n = p.DR[z]*p.DC[z];
  for (int i = blockIdx.x*256 + threadIdx.x; i < n; i += 800*256){
    int r = i / p.DC[z], c = i - r*p.DC[z];
    float v = (r < p.R[z] && c < p.C[z]) ? p.src[z][r*p.C[z] + c] : 0.f;
    p.dst[z][i] = f2bf(v);
  }
}
struct PrepB { const float* src[4]; float* dst[4]; };
__global__ void k_prepb(PrepB p){
  int z = blockIdx.y;
  int i = blockIdx.x*256 + threadIdx.x;
  if (i < 640) p.dst[z][i] = (i < GG) ? p.src[z][i] : 0.f;
}

// ---------------- embedding gather (sorted order) -> bf16 padded [Mc][KSTR] ----------------
__global__ void k_embed(const int* __restrict__ x, const float* __restrict__ emb,
                        const int* __restrict__ perm, int co, int Mc,
                        u16* __restrict__ xe){
  long idx = (long)blockIdx.x*256 + threadIdx.x;  // < Mc*40
  int row = (int)(idx / 40);
  if (row >= Mc) return;
  int c8  = ((int)(idx - (long)row*40)) * 8;
  int iloc = row >> 8;        // /SS
  int s    = row & 255;       // %SS
  int b    = perm[co + iloc];
  int tok  = x[b*SS + s];
  u16x8 v;
  #pragma unroll
  for (int e = 0; e < 8; ++e){
    int c = c8 + e;
    float f = (c < DD && tok != 0) ? emb[(size_t)tok*DD + c] : 0.f;
    v[e] = f2bf(f);
  }
  *(u16x8*)(xe + (size_t)row*KSTR + c8) = v;
}

// ---------------- big GEMM: out[m][n] = bf16( sum_k A[m][k]*W[n][k] + bias[n] ) ----------------
// A: [*, KSTR] bf16, W: [640][KSTR] bf16 padded, out stride GSTR (write cols < 600 only)
__launch_bounds__(512, 2)
__global__ void k_gemm(const u16* __restrict__ A,
                       const u16* __restrict__ Wf, const u16* __restrict__ Wb,
                       const float* __restrict__ bsf, const float* __restrict__ bsb,
                       u16* __restrict__ of, u16* __restrict__ ob)
{
  const u16* W = blockIdx.z ? Wb : Wf;
  const float* bias = blockIdx.z ? bsb : bsf;
  u16* outp = blockIdx.z ? ob : of;

  __shared__ u16 Al[128*40];   // [128 rows][32 k] pad->40
  __shared__ u16 Bl[320*40];   // [320 n-rows][32 k] pad->40

  int tid = threadIdx.x;
  int l = tid & 63, w = tid >> 6;
  int lo = l & 15, hi = l >> 4;
  int wm = w >> 2, wn = w & 3;
  int m0 = blockIdx.x * 128;
  int n0 = blockIdx.y * 320;

  f32x4 zero = {0.f, 0.f, 0.f, 0.f};
  f32x4 acc[4][5];
  #pragma unroll
  for (int a = 0; a < 4; ++a)
    #pragma unroll
    for (int b = 0; b < 5; ++b) acc[a][b] = zero;

  for (int kk = 0; kk < 10; ++kk){
    int k0 = kk*32;
    __syncthreads();
    {
      int r = tid >> 2, c8 = (tid & 3) * 8;
      *(u16x8*)&Al[r*40 + c8] = *(const u16x8*)(A + (size_t)(m0+r)*KSTR + k0 + c8);
      #pragma unroll
      for (int i = 0; i < 3; ++i){
        int ch = tid + i*512;
        if (ch < 1280){
          int rr = ch >> 2, cc = (ch & 3) * 8;
          *(u16x8*)&Bl[rr*40 + cc] = *(const u16x8*)(W + (size_t)(n0+rr)*KSTR + k0 + cc);
        }
      }
    }
    __syncthreads();
    u16x8 av[4], bv[5];
    #pragma unroll
    for (int mt = 0; mt < 4; ++mt)
      av[mt] = *(const u16x8*)&Al[(wm*64 + mt*16 + lo)*40 + hi*8];
    #pragma unroll
    for (int nt = 0; nt < 5; ++nt)
      bv[nt] = *(const u16x8*)&Bl[(wn*80 + nt*16 + lo)*40 + hi*8];
    #pragma unroll
    for (int mt = 0; mt < 4; ++mt)
      #pragma unroll
      for (int nt = 0; nt < 5; ++nt)
        acc[mt][nt] = __builtin_amdgcn_mfma_f32_16x16x32_bf16(
            __builtin_bit_cast(bf16x8, av[mt]),
            __builtin_bit_cast(bf16x8, bv[nt]),
            acc[mt][nt], 0, 0, 0);
  }

  #pragma unroll
  for (int mt = 0; mt < 4; ++mt){
    #pragma unroll
    for (int nt = 0; nt < 5; ++nt){
      int col = n0 + wn*80 + nt*16 + lo;
      if (col < GG){
        float bsv = bias[col];
        #pragma unroll
        for (int r = 0; r < 4; ++r){
          int row = m0 + wm*64 + mt*16 + hi*4 + r;
          outp[(size_t)row*GSTR + col] = f2bf(acc[mt][nt][r] + bsv);
        }
      }
    }
  }
}

// ---------------- fused recurrence: one WG = 16 samples (chunk-local), all timesteps ----------------
// grid: (tiles_in_chunk, 2); blockIdx.y = dir
__launch_bounds__(512, 2)
__global__ void k_rec(const u16* __restrict__ gf, const u16* __restrict__ gb,
                      const u16* __restrict__ WhF, const u16* __restrict__ WhB,
                      const int* __restrict__ len, const int* __restrict__ perm, int co,
                      u16* __restrict__ h1, float* __restrict__ lastf, int layer1)
{
  int dir  = blockIdx.y;
  int tile = blockIdx.x;
  const u16* xg  = dir ? gb : gf;
  const u16* Whh = dir ? WhB : WhF;

  __shared__ u16   hsm[16*168];   // bf16 h state [16][160 padK], stride 168
  __shared__ float csm[16*152];   // f32 c state
  __shared__ float gsm[16*612];   // f32 h-gate partials [16][600], stride 612
  __shared__ int Ls[16], rbL[16], bo[16];

  int tid = threadIdx.x;
  int l = tid & 63, w = tid >> 6;
  int lo = l & 15, hi = l >> 4;

  // persistent Whh B-fragments: wave w owns n-tiles w*5..w*5+4
  u16x8 bw[5][5];
  #pragma unroll
  for (int j = 0; j < 5; ++j){
    int n0 = (w*5 + j)*16 + lo;
    #pragma unroll
    for (int ks = 0; ks < 5; ++ks)
      bw[j][ks] = *(const u16x8*)(Whh + (size_t)n0*WK + ks*32 + hi*8);
  }
  for (int i = tid; i < 16*168; i += 512) hsm[i] = 0;
  for (int i = tid; i < 16*152; i += 512) csm[i] = 0.f;
  if (tid < 16){
    int b = perm[co + tile*16 + tid];
    Ls[tid]  = len[b];
    rbL[tid] = (tile*16 + tid)*SS;
    bo[tid]  = b;
  }
  __syncthreads();
  int maxL = Ls[15];   // ascending sort -> max of tile

  for (int t = 0; t < maxL; ++t){
    u16x8 av[5];
    #pragma unroll
    for (int ks = 0; ks < 5; ++ks)
      av[ks] = *(const u16x8*)&hsm[lo*168 + ks*32 + hi*8];
    f32x4 zero = {0.f,0.f,0.f,0.f};
    f32x4 acc[5];
    #pragma unroll
    for (int j = 0; j < 5; ++j) acc[j] = zero;
    #pragma unroll
    for (int ks = 0; ks < 5; ++ks)
      #pragma unroll
      for (int j = 0; j < 5; ++j)
        acc[j] = __builtin_amdgcn_mfma_f32_16x16x32_bf16(
            __builtin_bit_cast(bf16x8, av[ks]),
            __builtin_bit_cast(bf16x8, bw[j][ks]),
            acc[j], 0, 0, 0);
    #pragma unroll
    for (int j = 0; j < 5; ++j){
      int n = (w*5 + j)*16 + lo;
      if (n < GG){
        #pragma unroll
        for (int r = 0; r < 4; ++r)
          gsm[(hi*4 + r)*612 + n] = acc[j][r];
      }
    }
    __syncthreads();

    #pragma unroll
    for (int it5 = 0; it5 < 5; ++it5){
      int it = tid + it5*512;
      if (it < 2400){
        int i = it / 150, jj = it - i*150;
        int Li = Ls[i];
        if (t < Li){
          int s = dir ? (Li - 1 - t) : t;
          size_t row = (size_t)(rbL[i] + s);
          const u16* xr = xg + row*GSTR;
          float pi = gsm[i*612 +        jj] + bf2f(xr[jj]);
          float pf = gsm[i*612 + 150 +  jj] + bf2f(xr[150+jj]);
          float pg = gsm[i*612 + 300 +  jj] + bf2f(xr[300+jj]);
          float po = gsm[i*612 + 450 +  jj] + bf2f(xr[450+jj]);
          float ig = fsig(pi), fg = fsig(pf), g2 = ftanh_(pg), og = fsig(po);
          float c  = fg * csm[i*152 + jj] + ig * g2;
          float hn = og * ftanh_(c);
          csm[i*152 + jj] = c;
          hsm[i*168 + jj] = f2bf(hn);
          if (!layer1){
            h1[row*KSTR + dir*150 + jj] = f2bf(hn);
          } else {
            bool isl = dir ? (t == 0) : (t == Li - 1);
            if (isl){
              lastf[(size_t)bo[i]*304 + dir*150 + jj] = hn;
            }
          }
        }
      }
    }
    __syncthreads();
  }
}

// ---------------- classifier head (fp32): out = tanh(last@W1.T+b1)@W2.T+b2 ----------------
__global__ void k_cls(const float* __restrict__ lastf,
                      const float* __restrict__ W1, const float* __restrict__ b1,
                      const float* __restrict__ W2, const float* __restrict__ b2,
                      float* __restrict__ out)
{
  __shared__ float inb[16][304];
  __shared__ float mid[16][304];
  int r0 = blockIdx.x * 16;
  int tid = threadIdx.x;
  for (int i = tid; i < 16*300; i += 256){
    int r = i / 300, c = i - r*300;
    inb[r][c] = lastf[(size_t)(r0+r)*304 + c];
  }
  __syncthreads();
  for (int i = tid; i < 4800; i += 256){
    int r = i / 300, c = i - r*300;
    float a = b1[c];
    const float* wr = W1 + (size_t)c*300;
    for (int k = 0; k < 300; ++k) a += inb[r][k] * wr[k];
    mid[r][c] = ftanh_(a);
  }
  __syncthreads();
  for (int i = tid; i < 4800; i += 256){
    int r = i / 300, c = i - r*300;
    float a = b2[c];
    const float* wr = W2 + (size_t)c*300;
    for (int k = 0; k < 300; ++k) a += mid[r][k] * wr[k];
    out[(size_t)(r0+r)*300 + c] = a;
  }
}

extern "C" void kernel_launch(void* const* d_in, const int* in_sizes, int n_in,
                              void* d_out, int out_size, void* d_ws, size_t ws_size,
                              hipStream_t stream)
{
  const int*   x    = (const int*)d_in[0];
  const int*   mask = (const int*)d_in[1];
  const float* emb  = (const float*)d_in[2];
  const float* Wih[4] = {(const float*)d_in[3], (const float*)d_in[6],
                         (const float*)d_in[9], (const float*)d_in[12]};
  const float* Whh[4] = {(const float*)d_in[4], (const float*)d_in[7],
                         (const float*)d_in[10], (const float*)d_in[13]};
  const float* bs[4]  = {(const float*)d_in[5], (const float*)d_in[8],
                         (const float*)d_in[11], (const float*)d_in[14]};
  const float* W1 = (const float*)d_in[15];
  const float* b1 = (const float*)d_in[16];
  const float* W2 = (const float*)d_in[17];
  const float* b2 = (const float*)d_in[18];
  float* out = (float*)d_out;

  char* p = (char*)d_ws;
  auto alloc = [&](size_t bytes){ char* r = p; p += (bytes + 255) & ~(size_t)255; return r; };

  // fixed allocations first
  u16 *WihP[4], *WhhP[4];
  for (int i = 0; i < 4; ++i){
    WihP[i] = (u16*)alloc(640*320*2);
    WhhP[i] = (u16*)alloc(640*160*2);
  }
  float* biasP[4];
  for (int i = 0; i < 4; ++i) biasP[i] = (float*)alloc(640*4);
  int* len  = (int*)alloc(1024*4);
  int* perm = (int*)alloc(1024*4);
  float* lastf = (float*)alloc((size_t)1024*304*4);
  size_t fixed_end = (size_t)(p - (char*)d_ws);

  // choose chunk count so variable buffers fit in ws_size
  const size_t per_sample = (size_t)SS*KSTR*2 + 2*(size_t)SS*GSTR*2;  // 786432 B
  int nc = 32;
  const int cands[6] = {1, 2, 4, 8, 16, 32};
  for (int ci = 0; ci < 6; ++ci){
    size_t need = fixed_end + (size_t)(BB / cands[ci]) * per_sample + 8192;
    if (need <= ws_size){ nc = cands[ci]; break; }
  }
  const int Bc = BB / nc;
  const int Mc = Bc * SS;

  u16* xe    = (u16*)alloc((size_t)Mc*KSTR*2);   // chunk embeddings, reused as h1
  u16* gatef = (u16*)alloc((size_t)Mc*GSTR*2);
  u16* gateb = (u16*)alloc((size_t)Mc*GSTR*2);

  k_len <<<dim3(1024), dim3(256), 0, stream>>>(mask, len);
  k_sort<<<dim3(1),    dim3(1024),0, stream>>>(len, perm);

  PrepW pw;
  for (int i = 0; i < 4; ++i){
    pw.src[i] = Wih[i]; pw.dst[i] = WihP[i];
    pw.R[i] = GG; pw.C[i] = DD; pw.DR[i] = 640; pw.DC[i] = KSTR;
    pw.src[4+i] = Whh[i]; pw.dst[4+i] = WhhP[i];
    pw.R[4+i] = GG; pw.C[4+i] = HH; pw.DR[4+i] = 640; pw.DC[4+i] = WK;
  }
  k_prepw<<<dim3(800, 8), dim3(256), 0, stream>>>(pw);

  PrepB pb;
  for (int i = 0; i < 4; ++i){ pb.src[i] = bs[i]; pb.dst[i] = biasP[i]; }
  k_prepb<<<dim3(3, 4), dim3(256), 0, stream>>>(pb);

  for (int c = 0; c < nc; ++c){
    int co = c * Bc;
    k_embed<<<dim3(Bc*40), dim3(256), 0, stream>>>(x, emb, perm, co, Mc, xe);
    // layer 0
    k_gemm<<<dim3(Mc/128, 2, 2), dim3(512), 0, stream>>>(xe, WihP[0], WihP[1],
                                                         biasP[0], biasP[1], gatef, gateb);
    k_rec <<<dim3(Bc/16, 2), dim3(512), 0, stream>>>(gatef, gateb, WhhP[0], WhhP[1],
                                                     len, perm, co, xe, nullptr, 0);
    // layer 1
    k_gemm<<<dim3(Mc/128, 2, 2), dim3(512), 0, stream>>>(xe, WihP[2], WihP[3],
                                                         biasP[2], biasP[3], gatef, gateb);
    k_rec <<<dim3(Bc/16, 2), dim3(512), 0, stream>>>(gatef, gateb, WhhP[2], WhhP[3],
                                                     len, perm, co, nullptr, lastf, 1);
  }

  k_cls<<<dim3(64), dim3(256), 0, stream>>>(lastf, W1, b1, W2, b2, out);
}